// Round 1
// baseline (5579.147 us; speedup 1.0000x reference)
//
#include <hip/hip_runtime.h>
#include <hip/hip_bf16.h>
#include <math.h>

#define DIM   384
#define HEADS 6
#define HD    64
#define NB    16      // batch
#define HW    56
#define N1    (HW*HW)   // 3136
#define H2    28
#define N2    (H2*H2)   // 784
#define H3    14
#define N3    (H3*H3)   // 196
#define NT    49        // global tokens
#define HIDN  1536
#define SCL   0.125f

__device__ __forceinline__ float gelu_exact(float v){
    return 0.5f * v * (1.0f + erff(v * 0.70710678118654752f));
}

// ---------------- transpose conv weight [O,I,3,3] -> [tap,I,O] for coalesced reads
__global__ void k_wt(const float* __restrict__ w, float* __restrict__ wt, int total)
{
    int idx = blockIdx.x * 256 + threadIdx.x;
    if (idx >= total) return;
    int co   = idx % DIM;
    int rest = idx / DIM;
    int ci   = rest % DIM;
    int tap  = rest / DIM;
    wt[idx] = w[((size_t)co*DIM + ci)*9 + tap];
}

// ---------------- depthwise 3x3 conv + bias + LayerNorm(eps=1e-6) -> x_ln
__global__ __launch_bounds__(384)
void k_dwln(const float* __restrict__ x, const float* __restrict__ dww,
            const float* __restrict__ dwb, const float* __restrict__ g,
            const float* __restrict__ bt, float* __restrict__ out)
{
    const int pix = blockIdx.x;           // b*N1 + n
    const int b = pix / N1, n = pix % N1;
    const int h = n / HW, w = n % HW;
    const int c = threadIdx.x;
    float acc = dwb[c];
    #pragma unroll
    for (int kh = 0; kh < 3; ++kh){
        int ih = h + kh - 1; if (ih < 0 || ih >= HW) continue;
        #pragma unroll
        for (int kw = 0; kw < 3; ++kw){
            int iw = w + kw - 1; if (iw < 0 || iw >= HW) continue;
            acc += x[((size_t)(b*N1 + ih*HW + iw))*DIM + c] * dww[c*9 + kh*3 + kw];
        }
    }
    float s = acc, q = acc*acc;
    #pragma unroll
    for (int off = 32; off; off >>= 1){ s += __shfl_down(s, off); q += __shfl_down(q, off); }
    __shared__ float rs[6], rq[6];
    int lane = threadIdx.x & 63, wv = threadIdx.x >> 6;
    if (!lane){ rs[wv] = s; rq[wv] = q; }
    __syncthreads();
    float ts = 0.f, tq = 0.f;
    #pragma unroll
    for (int i = 0; i < 6; ++i){ ts += rs[i]; tq += rq[i]; }
    float mean = ts * (1.f/DIM);
    float var  = tq * (1.f/DIM) - mean*mean;
    float rstd = rsqrtf(var + 1e-6f);
    out[(size_t)pix*DIM + c] = (acc - mean) * rstd * g[c] + bt[c];
}

// ---------------- fused MLP: out = x + gamma*( gelu(xln@W1+b1)@W2 + b2 )
// 16 tokens/block, hidden processed in 128-wide chunks through LDS.
__global__ __launch_bounds__(256)
void k_mlp(const float* __restrict__ xln, const float* __restrict__ x,
           const float* __restrict__ w1, const float* __restrict__ b1,
           const float* __restrict__ w2, const float* __restrict__ b2,
           const float* __restrict__ gamma, float* __restrict__ out)
{
    const int t0  = blockIdx.x * 16;
    const int tid = threadIdx.x;
    __shared__ float xt[16*DIM];     // 24 KB
    __shared__ float hid[16*128];    // 8 KB
    for (int i = tid*4; i < 16*DIM; i += 1024)
        *(float4*)&xt[i] = *(const float4*)&xln[(size_t)t0*DIM + i];
    __syncthreads();
    const int tp = tid >> 5;      // 0..7 : tokens {tp, tp+8} in pw1
    const int hl = tid & 31;      // pw1 col block: (hl*4 + j)
    const int tq = tid >> 6;      // 0..3 : tokens tq*4..tq*4+3 in pw2
    const int cg = tid & 63;      // pw2 cols: cg + 64*j
    float oacc[24];
    #pragma unroll
    for (int i = 0; i < 24; ++i) oacc[i] = 0.f;

    for (int ch = 0; ch < 12; ++ch){
        const int hc0 = ch * 128;
        float ha0[4] = {0,0,0,0}, ha1[4] = {0,0,0,0};
        for (int c = 0; c < DIM; ++c){
            float x0 = xt[tp*DIM + c];
            float x1 = xt[(tp+8)*DIM + c];
            float4 w4 = *(const float4*)&w1[(size_t)c*HIDN + hc0 + hl*4];
            ha0[0] += x0*w4.x; ha0[1] += x0*w4.y; ha0[2] += x0*w4.z; ha0[3] += x0*w4.w;
            ha1[0] += x1*w4.x; ha1[1] += x1*w4.y; ha1[2] += x1*w4.z; ha1[3] += x1*w4.w;
        }
        float4 bb = *(const float4*)&b1[hc0 + hl*4];
        float bbv[4] = {bb.x, bb.y, bb.z, bb.w};
        #pragma unroll
        for (int j = 0; j < 4; ++j){
            hid[tp*128     + hl*4 + j] = gelu_exact(ha0[j] + bbv[j]);
            hid[(tp+8)*128 + hl*4 + j] = gelu_exact(ha1[j] + bbv[j]);
        }
        __syncthreads();
        for (int hh = 0; hh < 128; ++hh){
            float pv0 = hid[(tq*4+0)*128 + hh];
            float pv1 = hid[(tq*4+1)*128 + hh];
            float pv2 = hid[(tq*4+2)*128 + hh];
            float pv3 = hid[(tq*4+3)*128 + hh];
            const float* w2row = &w2[(size_t)(hc0+hh)*DIM + cg];
            #pragma unroll
            for (int j = 0; j < 6; ++j){
                float wv = w2row[64*j];
                oacc[j*4+0] += pv0 * wv;
                oacc[j*4+1] += pv1 * wv;
                oacc[j*4+2] += pv2 * wv;
                oacc[j*4+3] += pv3 * wv;
            }
        }
        __syncthreads();
    }
    #pragma unroll
    for (int j = 0; j < 6; ++j){
        int c = cg + 64*j;
        float gmm = gamma[c], bb2 = b2[c];
        #pragma unroll
        for (int tt = 0; tt < 4; ++tt){
            size_t idx = (size_t)(t0 + tq*4 + tt)*DIM + c;
            out[idx] = x[idx] + gmm * (oacc[j*4+tt] + bb2);
        }
    }
}

// ---------------- 2x2 avg pool, NHWC
__global__ __launch_bounds__(384)
void k_pool(const float* __restrict__ in, float* __restrict__ out, int Hin)
{
    int Ho = Hin >> 1;
    int pix = blockIdx.x;           // b*Ho*Ho + oh*Ho + ow
    int b = pix / (Ho*Ho), r = pix % (Ho*Ho);
    int oh = r / Ho, ow = r % Ho;
    int c = threadIdx.x;
    size_t base = ((size_t)b * Hin * Hin + (size_t)(2*oh)*Hin + 2*ow) * DIM;
    const float* p00 = &in[base];
    const float* p01 = p00 + DIM;
    const float* p10 = p00 + (size_t)Hin*DIM;
    const float* p11 = p10 + DIM;
    out[(size_t)pix*DIM + c] = 0.25f * (p00[c] + p01[c] + p10[c] + p11[c]);
}

// ---------------- full 3x3 conv (C->C, no bias) + LN(eps=1e-5) + ReLU on 28x28
// one block = 7 output pixels of one row; weights pre-transposed to [tap][ci][co]
__global__ __launch_bounds__(384)
void k_conv(const float* __restrict__ in, const float* __restrict__ wt,
            const float* __restrict__ g, const float* __restrict__ bt,
            float* __restrict__ out)
{
    int bx  = blockIdx.x;            // b*112 + oh*4 + owt
    int owt = bx & 3;
    int oh  = (bx >> 2) % H2;
    int b   = bx / (4*H2);
    int ow0 = owt * 7;
    int c   = threadIdx.x;
    __shared__ float tile[27*DIM];   // 3 rows x 9 cols x 384 ch = 41.5 KB
    for (int t = 0; t < 27; ++t){
        int rr = t / 9, cc = t % 9;
        int ih = oh - 1 + rr, iw = ow0 - 1 + cc;
        float v = 0.f;
        if (ih >= 0 && ih < H2 && iw >= 0 && iw < H2)
            v = in[((size_t)(b*N2 + ih*H2 + iw))*DIM + c];
        tile[t*DIM + c] = v;
    }
    __syncthreads();
    float acc[7];
    #pragma unroll
    for (int p = 0; p < 7; ++p) acc[p] = 0.f;
    for (int ci = 0; ci < DIM; ++ci){
        float iv[27];
        #pragma unroll
        for (int t = 0; t < 27; ++t) iv[t] = tile[t*DIM + ci];
        #pragma unroll
        for (int tap = 0; tap < 9; ++tap){
            int kh = tap / 3, kw = tap % 3;
            float wv = wt[((size_t)tap*DIM + ci)*DIM + c];
            #pragma unroll
            for (int p = 0; p < 7; ++p)
                acc[p] += iv[kh*9 + p + kw] * wv;
        }
    }
    __shared__ float rs[6], rq[6];
    int lane = threadIdx.x & 63, wv_ = threadIdx.x >> 6;
    for (int p = 0; p < 7; ++p){
        float v = acc[p];
        float s = v, q = v*v;
        #pragma unroll
        for (int off = 32; off; off >>= 1){ s += __shfl_down(s, off); q += __shfl_down(q, off); }
        if (!lane){ rs[wv_] = s; rq[wv_] = q; }
        __syncthreads();
        float ts = 0.f, tq2 = 0.f;
        #pragma unroll
        for (int i = 0; i < 6; ++i){ ts += rs[i]; tq2 += rq[i]; }
        float mean = ts * (1.f/DIM);
        float var  = tq2 * (1.f/DIM) - mean*mean;
        float rstd = rsqrtf(var + 1e-5f);
        float o = (v - mean) * rstd * g[c] + bt[c];
        out[((size_t)(b*N2 + oh*H2 + ow0 + p))*DIM + c] = fmaxf(o, 0.f);
        __syncthreads();
    }
}

// ---------------- generic GEMM: out[M,N] = A[M,K] @ W[K,N] (+bias). 16x64 tile.
__global__ __launch_bounds__(256)
void k_gemm(const float* __restrict__ A, int lda,
            const float* __restrict__ W, const float* __restrict__ bias,
            float* __restrict__ out, int ldo, int K, int nb)
{
    int bx = blockIdx.x;
    int m0 = (bx / nb) * 16;
    int cb = (bx % nb) * 64;
    int tid = threadIdx.x;
    int r  = tid >> 4;         // 0..15
    int cg = tid & 15;         // *4 cols
    int N  = nb * 64;          // W row stride
    __shared__ float As[16*32];
    __shared__ float Ws[32*64];
    float acc[4] = {0,0,0,0};
    for (int k0 = 0; k0 < K; k0 += 32){
        int e = tid;
        #pragma unroll
        for (int i = 0; i < 2; ++i){
            int rr = e >> 5, kk = e & 31;
            As[rr*32 + kk] = A[(size_t)(m0+rr)*lda + k0 + kk];
            e += 256;
        }
        int f = tid;
        #pragma unroll
        for (int i = 0; i < 8; ++i){
            int kr = f >> 6, cc = f & 63;
            Ws[kr*64 + cc] = W[(size_t)(k0+kr)*N + cb + cc];
            f += 256;
        }
        __syncthreads();
        #pragma unroll 8
        for (int kk = 0; kk < 32; ++kk){
            float a = As[r*32 + kk];
            #pragma unroll
            for (int j = 0; j < 4; ++j)
                acc[j] += a * Ws[kk*64 + cg*4 + j];
        }
        __syncthreads();
    }
    #pragma unroll
    for (int j = 0; j < 4; ++j){
        int c = cb + cg*4 + j;
        float v = acc[j] + (bias ? bias[c] : 0.f);
        out[(size_t)(m0 + r)*ldo + c] = v;
    }
}

// ---------------- generic MHA: 32-query tile per block; heads concat on write.
// optional addp: out = addp + attn (residual fuse, may alias out)
__global__ __launch_bounds__(256)
void k_attn(const float* __restrict__ qp, int ldq,
            const float* __restrict__ kp, const float* __restrict__ vp, int ldkv,
            float* __restrict__ op, int ldo,
            const float* __restrict__ addp,
            int Nq, int Nk, int qtiles)
{
    int bx = blockIdx.x;
    int qt = bx % qtiles;
    int h  = (bx / qtiles) % HEADS;
    int b  = bx / (qtiles * HEADS);
    int q0 = qt * 32;
    const float* qb = qp + (size_t)b*Nq*ldq + h*HD;
    const float* kb = kp + (size_t)b*Nk*ldkv + h*HD;
    const float* vb = vp + (size_t)b*Nk*ldkv + h*HD;
    int tid = threadIdx.x;
    __shared__ float Q[32*HD];       // 8 KB (pre-scaled)
    __shared__ float S[32*196];      // 24.5 KB
    for (int e = tid; e < 32*HD; e += 256){
        int r = e >> 6, d = e & 63;
        Q[e] = (q0 + r < Nq) ? qb[(size_t)(q0+r)*ldq + d] * SCL : 0.f;
    }
    __syncthreads();
    for (int s = tid; s < 32*Nk; s += 256){
        int qi = s / Nk, ki = s - qi*Nk;
        if (q0 + qi < Nq){
            const float* kr = &kb[(size_t)ki*ldkv];
            float dot = 0.f;
            #pragma unroll 16
            for (int d = 0; d < HD; ++d) dot += Q[qi*HD + d] * kr[d];
            S[qi*196 + ki] = dot;
        }
    }
    __syncthreads();
    {   // softmax: 8 threads per row
        int r = tid >> 3, sub = tid & 7;
        if (q0 + r < Nq){
            float m = -1e30f;
            for (int k = sub; k < Nk; k += 8) m = fmaxf(m, S[r*196 + k]);
            #pragma unroll
            for (int off = 4; off; off >>= 1) m = fmaxf(m, __shfl_xor(m, off, 8));
            float sum = 0.f;
            for (int k = sub; k < Nk; k += 8){
                float e = __expf(S[r*196 + k] - m);
                S[r*196 + k] = e;
                sum += e;
            }
            #pragma unroll
            for (int off = 4; off; off >>= 1) sum += __shfl_xor(sum, off, 8);
            float inv = 1.f / sum;
            for (int k = sub; k < Nk; k += 8) S[r*196 + k] *= inv;
        }
    }
    __syncthreads();
    {   // PV: thread = (query, 8-channel slice)
        int qi = tid >> 3, d0 = (tid & 7) * 8;
        if (q0 + qi < Nq){
            float o[8] = {0,0,0,0,0,0,0,0};
            for (int k = 0; k < Nk; ++k){
                float p = S[qi*196 + k];
                const float* vr = &vb[(size_t)k*ldkv + d0];
                #pragma unroll
                for (int j = 0; j < 8; ++j) o[j] += p * vr[j];
            }
            size_t ob = (size_t)(b*Nq + q0 + qi)*ldo + h*HD + d0;
            #pragma unroll
            for (int j = 0; j < 8; ++j){
                float v = o[j];
                if (addp) v += addp[ob + j];
                op[ob + j] = v;
            }
        }
    }
}

extern "C" void kernel_launch(void* const* d_in, const int* in_sizes, int n_in,
                              void* d_out, int out_size, void* d_ws, size_t ws_size,
                              hipStream_t stream)
{
    const float* x    = (const float*)d_in[0];
    const float* gtok = (const float*)d_in[1];
    const float* dww  = (const float*)d_in[2];
    const float* dwb  = (const float*)d_in[3];
    const float* lng  = (const float*)d_in[4];
    const float* lnb  = (const float*)d_in[5];
    const float* w1   = (const float*)d_in[6];
    const float* b1   = (const float*)d_in[7];
    const float* w2   = (const float*)d_in[8];
    const float* b2   = (const float*)d_in[9];
    const float* gma  = (const float*)d_in[10];
    const float* cbw  = (const float*)d_in[11];
    const float* cbg  = (const float*)d_in[12];
    const float* cbb  = (const float*)d_in[13];
    const float* qkvw = (const float*)d_in[14];
    const float* ugkv = (const float*)d_in[15];
    const float* ugq  = (const float*)d_in[16];
    const float* gbkv = (const float*)d_in[17];
    const float* gbq  = (const float*)d_in[18];
    const float* pw   = (const float*)d_in[19];
    const float* pb   = (const float*)d_in[20];

    float* ws    = (float*)d_ws;
    float* xln   = ws;                              // [B*N1, 384]
    float* xloc  = xln   + (size_t)NB*N1*DIM;       // [B*N1, 384]
    float* pool1 = xloc  + (size_t)NB*N1*DIM;       // [B*N2, 384]
    float* cbout = pool1 + (size_t)NB*N2*DIM;       // [B*N2, 384]
    float* xd    = cbout + (size_t)NB*N2*DIM;       // [B*N3, 384]
    float* qkv   = xd    + (size_t)NB*N3*DIM;       // [B*N3, 1152]
    float* xds   = qkv   + (size_t)NB*N3*3*DIM;     // [B*N3, 384]
    float* k2v2  = xds   + (size_t)NB*N3*DIM;       // [B*N3, 768]
    float* gq    = k2v2  + (size_t)NB*N3*2*DIM;     // [B*NT, 384]
    float* k3v3  = gq    + (size_t)NB*NT*DIM;       // [B*NT, 768]
    float* wt    = k3v3  + (size_t)NB*NT*2*DIM;     // [9*384*384]
    float* q3    = xln;  // reuse: xln dead after k_mlp

    float* xout = (float*)d_out;
    float* gt   = xout + (size_t)NB*N1*DIM;

    // ConvEncoder (layer-scaled residual branch)
    k_wt  <<<(DIM*DIM*9 + 255)/256, 256, 0, stream>>>(cbw, wt, DIM*DIM*9);
    k_dwln<<<NB*N1, 384, 0, stream>>>(x, dww, dwb, lng, lnb, xln);
    k_mlp <<<NB*N1/16, 256, 0, stream>>>(xln, x, w1, b1, w2, b2, gma, xloc);
    // down_1 -> ConvBNReLU -> down_2
    k_pool<<<NB*N2, 384, 0, stream>>>(xloc, pool1, HW);
    k_conv<<<NB*H2*4, 384, 0, stream>>>(pool1, wt, cbg, cbb, cbout);
    k_pool<<<NB*N3, 384, 0, stream>>>(cbout, xd, H2);
    // global aggregation (MHSA over 196 tokens)
    k_gemm<<<(NB*N3/16)*(3*DIM/64), 256, 0, stream>>>(xd, DIM, qkvw, nullptr, qkv, 3*DIM, DIM, 3*DIM/64);
    k_attn<<<NB*HEADS*7, 256, 0, stream>>>(qkv, 3*DIM, qkv+DIM, qkv+2*DIM, 3*DIM, xds, DIM, nullptr, N3, N3, 7);
    // global token update (q = global tokens)
    k_gemm<<<(NB*N3/16)*(2*DIM/64), 256, 0, stream>>>(xds, DIM, ugkv, nullptr, k2v2, 2*DIM, DIM, 2*DIM/64);
    k_gemm<<<(NB*NT/16)*(DIM/64), 256, 0, stream>>>(gtok, DIM, ugq, nullptr, gq, DIM, DIM, DIM/64);
    k_attn<<<NB*HEADS*2, 256, 0, stream>>>(gq, DIM, k2v2, k2v2+DIM, 2*DIM, gt, DIM, nullptr, NT, N3, 2);
    // global broadcast (q = image tokens, kv = 49 global tokens); fuse x_local+x_global
    k_gemm<<<(NB*NT/16)*(2*DIM/64), 256, 0, stream>>>(gt, DIM, gbkv, nullptr, k3v3, 2*DIM, DIM, 2*DIM/64);
    k_gemm<<<(NB*N1/16)*(DIM/64), 256, 0, stream>>>(x, DIM, gbq, nullptr, q3, DIM, DIM, DIM/64);
    k_attn<<<NB*HEADS*98, 256, 0, stream>>>(q3, DIM, k3v3, k3v3+DIM, 2*DIM, xloc, DIM, xloc, N1, NT, 98);
    // final projection
    k_gemm<<<(NB*N1/16)*(DIM/64), 256, 0, stream>>>(xloc, DIM, pw, pb, xout, DIM, DIM, DIM/64);
}

// Round 2
// 3024.695 us; speedup vs baseline: 1.8445x; 1.8445x over previous
//
#include <hip/hip_runtime.h>
#include <hip/hip_bf16.h>
#include <math.h>

#define DIM   384
#define HEADS 6
#define HD    64
#define NB    16      // batch
#define HW    56
#define N1    (HW*HW)   // 3136
#define H2    28
#define N2    (H2*H2)   // 784
#define H3    14
#define N3    (H3*H3)   // 196
#define NT    49        // global tokens
#define HIDN  1536
#define SCL   0.125f

typedef short s8v __attribute__((ext_vector_type(8)));   // 8 bf16 (4 VGPRs)
typedef float f4v __attribute__((ext_vector_type(4)));   // MFMA accumulator

__device__ __forceinline__ short f2b(float f){           // f32 -> bf16 RNE
    unsigned u = __builtin_bit_cast(unsigned, f);
    unsigned r = (u + 0x7FFFu + ((u >> 16) & 1u)) >> 16;
    return (short)r;
}
__device__ __forceinline__ float b2f(short s){
    return __builtin_bit_cast(float, ((unsigned)(unsigned short)s) << 16);
}

// ---------------- transpose conv weight [O,I,3,3] -> [tap,I,O]
__global__ void k_wt(const float* __restrict__ w, float* __restrict__ wt, int total)
{
    int idx = blockIdx.x * 256 + threadIdx.x;
    if (idx >= total) return;
    int co   = idx % DIM;
    int rest = idx / DIM;
    int ci   = rest % DIM;
    int tap  = rest / DIM;
    wt[idx] = w[((size_t)co*DIM + ci)*9 + tap];
}

// ---------------- tiled transpose + cvt: src f32 [R][C] -> dst bf16 [C][R]
__global__ __launch_bounds__(256)
void k_tcvt(const float* __restrict__ src, short* __restrict__ dst, int R, int C, int rt)
{
    int tile = blockIdx.x;
    int tr = tile % rt, tc = tile / rt;
    int r0 = tr*32, c0 = tc*32;
    int tx = threadIdx.x & 31, ty = threadIdx.x >> 5;
    __shared__ float t[32][33];
    #pragma unroll
    for (int j = 0; j < 4; ++j)
        t[ty + j*8][tx] = src[(size_t)(r0 + ty + j*8)*C + c0 + tx];
    __syncthreads();
    #pragma unroll
    for (int j = 0; j < 4; ++j)
        dst[(size_t)(c0 + ty + j*8)*R + r0 + tx] = f2b(t[tx][ty + j*8]);
}

// ---------------- depthwise 3x3 conv + bias + LayerNorm(1e-6) -> bf16 out
__global__ __launch_bounds__(384)
void k_dwln(const float* __restrict__ x, const float* __restrict__ dww,
            const float* __restrict__ dwb, const float* __restrict__ g,
            const float* __restrict__ bt, short* __restrict__ out)
{
    const int pix = blockIdx.x;           // b*N1 + n
    const int b = pix / N1, n = pix % N1;
    const int h = n / HW, w = n % HW;
    const int c = threadIdx.x;
    float acc = dwb[c];
    #pragma unroll
    for (int kh = 0; kh < 3; ++kh){
        int ih = h + kh - 1; if (ih < 0 || ih >= HW) continue;
        #pragma unroll
        for (int kw = 0; kw < 3; ++kw){
            int iw = w + kw - 1; if (iw < 0 || iw >= HW) continue;
            acc += x[((size_t)(b*N1 + ih*HW + iw))*DIM + c] * dww[c*9 + kh*3 + kw];
        }
    }
    float s = acc, q = acc*acc;
    #pragma unroll
    for (int off = 32; off; off >>= 1){ s += __shfl_down(s, off); q += __shfl_down(q, off); }
    __shared__ float rs[6], rq[6];
    int lane = threadIdx.x & 63, wv = threadIdx.x >> 6;
    if (!lane){ rs[wv] = s; rq[wv] = q; }
    __syncthreads();
    float ts = 0.f, tq = 0.f;
    #pragma unroll
    for (int i = 0; i < 6; ++i){ ts += rs[i]; tq += rq[i]; }
    float mean = ts * (1.f/DIM);
    float var  = tq * (1.f/DIM) - mean*mean;
    float rstd = rsqrtf(var + 1e-6f);
    out[(size_t)pix*DIM + c] = f2b((acc - mean) * rstd * g[c] + bt[c]);
}

// ---------------- fused MFMA MLP: out = x + gamma*( gelu(xb@W1+b1)@W2 + b2 )
// 64 tokens/block, 4 waves; hidden chunked 64-wide through LDS.
#define XS_STR 392   // 64x392 shorts = 50176 B  (pad: 2-way bank alias only)
#define HS_STR 72    // 64x72  shorts = 9216  B
__global__ __launch_bounds__(256)
void k_mlp_mfma(const short* __restrict__ xb, const float* __restrict__ x,
                const short* __restrict__ w1t, const float* __restrict__ b1,
                const short* __restrict__ w2t, const float* __restrict__ b2,
                const float* __restrict__ gamma, float* __restrict__ out)
{
    __shared__ short Xs[64*XS_STR];
    __shared__ short Hs[64*HS_STR];
    const int t0  = blockIdx.x * 64;
    const int tid = threadIdx.x;
    const int w   = tid >> 6;
    const int l   = tid & 63;
    const int lr  = l & 15;        // frag row/col within 16
    const int lg  = l >> 4;        // k-group / row-group

    // stage X tile (bf16) into LDS, 16B chunks
    #pragma unroll
    for (int it = 0; it < 12; ++it){
        int i = tid + it*256;            // 64 rows * 48 chunks
        int row = i / 48, c8 = (i % 48) * 8;
        *(s8v*)&Xs[row*XS_STR + c8] = *(const s8v*)&xb[(size_t)(t0+row)*DIM + c8];
    }
    __syncthreads();

    f4v a2[4][6];
    #pragma unroll
    for (int m = 0; m < 4; ++m)
        #pragma unroll
        for (int n = 0; n < 6; ++n) a2[m][n] = (f4v){0.f,0.f,0.f,0.f};

    for (int ch = 0; ch < 24; ++ch){
        const int hc0 = ch * 64;
        // ---- phase 1: H[:, w*16..+15] = gelu(X @ W1 + b1)
        f4v a1[4];
        #pragma unroll
        for (int m = 0; m < 4; ++m) a1[m] = (f4v){0.f,0.f,0.f,0.f};
        const int col1 = w*16 + lr;                  // chunk-local hidden col
        #pragma unroll 4
        for (int ks = 0; ks < 12; ++ks){
            const int k0 = ks*32 + lg*8;
            s8v bv = *(const s8v*)&w1t[(size_t)(hc0 + col1)*DIM + k0];
            #pragma unroll
            for (int m = 0; m < 4; ++m){
                s8v av = *(const s8v*)&Xs[(m*16 + lr)*XS_STR + k0];
                a1[m] = __builtin_amdgcn_mfma_f32_16x16x32_bf16(av, bv, a1[m], 0, 0, 0);
            }
        }
        float bb1 = b1[hc0 + col1];
        #pragma unroll
        for (int m = 0; m < 4; ++m){
            #pragma unroll
            for (int r = 0; r < 4; ++r){
                float h = a1[m][r] + bb1;
                float gl = h / (1.f + __expf(-1.702f * h));   // fast gelu (scaled by 1e-6 later)
                Hs[(m*16 + lg*4 + r)*HS_STR + col1] = f2b(gl);
            }
        }
        __syncthreads();
        // ---- phase 2: acc += H @ W2chunk   (wave covers cols w*96..+95)
        #pragma unroll
        for (int ks = 0; ks < 2; ++ks){
            const int k0 = ks*32 + lg*8;
            s8v av[4];
            #pragma unroll
            for (int m = 0; m < 4; ++m)
                av[m] = *(const s8v*)&Hs[(m*16 + lr)*HS_STR + k0];
            #pragma unroll
            for (int n = 0; n < 6; ++n){
                s8v bv = *(const s8v*)&w2t[(size_t)(w*96 + n*16 + lr)*HIDN + hc0 + k0];
                #pragma unroll
                for (int m = 0; m < 4; ++m)
                    a2[m][n] = __builtin_amdgcn_mfma_f32_16x16x32_bf16(av[m], bv, a2[m][n], 0, 0, 0);
            }
        }
        __syncthreads();
    }
    // ---- epilogue: residual + layer scale
    #pragma unroll
    for (int n = 0; n < 6; ++n){
        const int col = w*96 + n*16 + lr;
        const float gm = gamma[col], bb2 = b2[col];
        #pragma unroll
        for (int m = 0; m < 4; ++m){
            #pragma unroll
            for (int r = 0; r < 4; ++r){
                size_t idx = (size_t)(t0 + m*16 + lg*4 + r)*DIM + col;
                out[idx] = x[idx] + gm * (a2[m][n][r] + bb2);
            }
        }
    }
}

// ---------------- MFMA GEMM: C[M,384] = A[M,384] @ WT^T (+bias), out f32 or bf16
__global__ __launch_bounds__(256)
void k_gemm_mfma(const float* __restrict__ A, const short* __restrict__ WT,
                 const float* __restrict__ bias, float* __restrict__ outf,
                 short* __restrict__ outb)
{
    __shared__ short As[64*XS_STR];
    const int t0  = blockIdx.x * 64;
    const int tid = threadIdx.x;
    const int w   = tid >> 6;
    const int l   = tid & 63;
    const int lr  = l & 15;
    const int lg  = l >> 4;

    #pragma unroll
    for (int it = 0; it < 12; ++it){
        int i = tid + it*256;
        int row = i / 48, c8 = (i % 48) * 8;
        const float4* p = (const float4*)&A[(size_t)(t0+row)*DIM + c8];
        float4 u = p[0], v = p[1];
        s8v pk;
        pk[0]=f2b(u.x); pk[1]=f2b(u.y); pk[2]=f2b(u.z); pk[3]=f2b(u.w);
        pk[4]=f2b(v.x); pk[5]=f2b(v.y); pk[6]=f2b(v.z); pk[7]=f2b(v.w);
        *(s8v*)&As[row*XS_STR + c8] = pk;
    }
    __syncthreads();

    f4v a2[4][6];
    #pragma unroll
    for (int m = 0; m < 4; ++m)
        #pragma unroll
        for (int n = 0; n < 6; ++n) a2[m][n] = (f4v){0.f,0.f,0.f,0.f};

    #pragma unroll 4
    for (int ks = 0; ks < 12; ++ks){
        const int k0 = ks*32 + lg*8;
        s8v av[4];
        #pragma unroll
        for (int m = 0; m < 4; ++m)
            av[m] = *(const s8v*)&As[(m*16 + lr)*XS_STR + k0];
        #pragma unroll
        for (int n = 0; n < 6; ++n){
            s8v bv = *(const s8v*)&WT[(size_t)(w*96 + n*16 + lr)*DIM + k0];
            #pragma unroll
            for (int m = 0; m < 4; ++m)
                a2[m][n] = __builtin_amdgcn_mfma_f32_16x16x32_bf16(av[m], bv, a2[m][n], 0, 0, 0);
        }
    }
    #pragma unroll
    for (int n = 0; n < 6; ++n){
        const int col = w*96 + n*16 + lr;
        const float bb = bias ? bias[col] : 0.f;
        #pragma unroll
        for (int m = 0; m < 4; ++m){
            #pragma unroll
            for (int r = 0; r < 4; ++r){
                size_t idx = (size_t)(t0 + m*16 + lg*4 + r)*DIM + col;
                float v = a2[m][n][r] + bb;
                if (outb) outb[idx] = f2b(v);
                else      outf[idx] = v;
            }
        }
    }
}

// ---------------- 2x2 avg pool, NHWC
__global__ __launch_bounds__(384)
void k_pool(const float* __restrict__ in, float* __restrict__ out, int Hin)
{
    int Ho = Hin >> 1;
    int pix = blockIdx.x;
    int b = pix / (Ho*Ho), r = pix % (Ho*Ho);
    int oh = r / Ho, ow = r % Ho;
    int c = threadIdx.x;
    size_t base = ((size_t)b * Hin * Hin + (size_t)(2*oh)*Hin + 2*ow) * DIM;
    const float* p00 = &in[base];
    const float* p01 = p00 + DIM;
    const float* p10 = p00 + (size_t)Hin*DIM;
    const float* p11 = p10 + DIM;
    out[(size_t)pix*DIM + c] = 0.25f * (p00[c] + p01[c] + p10[c] + p11[c]);
}

// ---------------- full 3x3 conv (C->C) + LN(1e-5) + ReLU on 28x28
__global__ __launch_bounds__(384)
void k_conv(const float* __restrict__ in, const float* __restrict__ wt,
            const float* __restrict__ g, const float* __restrict__ bt,
            float* __restrict__ out)
{
    int bx  = blockIdx.x;
    int owt = bx & 3;
    int oh  = (bx >> 2) % H2;
    int b   = bx / (4*H2);
    int ow0 = owt * 7;
    int c   = threadIdx.x;
    __shared__ float tile[27*DIM];
    for (int t = 0; t < 27; ++t){
        int rr = t / 9, cc = t % 9;
        int ih = oh - 1 + rr, iw = ow0 - 1 + cc;
        float v = 0.f;
        if (ih >= 0 && ih < H2 && iw >= 0 && iw < H2)
            v = in[((size_t)(b*N2 + ih*H2 + iw))*DIM + c];
        tile[t*DIM + c] = v;
    }
    __syncthreads();
    float acc[7];
    #pragma unroll
    for (int p = 0; p < 7; ++p) acc[p] = 0.f;
    for (int ci = 0; ci < DIM; ++ci){
        float iv[27];
        #pragma unroll
        for (int t = 0; t < 27; ++t) iv[t] = tile[t*DIM + ci];
        #pragma unroll
        for (int tap = 0; tap < 9; ++tap){
            int kh = tap / 3, kw = tap % 3;
            float wv = wt[((size_t)tap*DIM + ci)*DIM + c];
            #pragma unroll
            for (int p = 0; p < 7; ++p)
                acc[p] += iv[kh*9 + p + kw] * wv;
        }
    }
    __shared__ float rs[6], rq[6];
    int lane = threadIdx.x & 63, wv_ = threadIdx.x >> 6;
    for (int p = 0; p < 7; ++p){
        float v = acc[p];
        float s = v, q = v*v;
        #pragma unroll
        for (int off = 32; off; off >>= 1){ s += __shfl_down(s, off); q += __shfl_down(q, off); }
        if (!lane){ rs[wv_] = s; rq[wv_] = q; }
        __syncthreads();
        float ts = 0.f, tq2 = 0.f;
        #pragma unroll
        for (int i = 0; i < 6; ++i){ ts += rs[i]; tq2 += rq[i]; }
        float mean = ts * (1.f/DIM);
        float var  = tq2 * (1.f/DIM) - mean*mean;
        float rstd = rsqrtf(var + 1e-5f);
        float o = (v - mean) * rstd * g[c] + bt[c];
        out[((size_t)(b*N2 + oh*H2 + ow0 + p))*DIM + c] = fmaxf(o, 0.f);
        __syncthreads();
    }
}

// ---------------- f32 GEMM (small shapes): out[M,N] = A[M,K] @ W[K,N] (+bias)
__global__ __launch_bounds__(256)
void k_gemm(const float* __restrict__ A, int lda,
            const float* __restrict__ W, const float* __restrict__ bias,
            float* __restrict__ out, int ldo, int K, int nb)
{
    int bx = blockIdx.x;
    int m0 = (bx / nb) * 16;
    int cb = (bx % nb) * 64;
    int tid = threadIdx.x;
    int r  = tid >> 4;
    int cg = tid & 15;
    int N  = nb * 64;
    __shared__ float As[16*32];
    __shared__ float Ws[32*64];
    float acc[4] = {0,0,0,0};
    for (int k0 = 0; k0 < K; k0 += 32){
        int e = tid;
        #pragma unroll
        for (int i = 0; i < 2; ++i){
            int rr = e >> 5, kk = e & 31;
            As[rr*32 + kk] = A[(size_t)(m0+rr)*lda + k0 + kk];
            e += 256;
        }
        int f = tid;
        #pragma unroll
        for (int i = 0; i < 8; ++i){
            int kr = f >> 6, cc = f & 63;
            Ws[kr*64 + cc] = W[(size_t)(k0+kr)*N + cb + cc];
            f += 256;
        }
        __syncthreads();
        #pragma unroll 8
        for (int kk = 0; kk < 32; ++kk){
            float a = As[r*32 + kk];
            #pragma unroll
            for (int j = 0; j < 4; ++j)
                acc[j] += a * Ws[kk*64 + cg*4 + j];
        }
        __syncthreads();
    }
    #pragma unroll
    for (int j = 0; j < 4; ++j){
        int c = cb + cg*4 + j;
        float v = acc[j] + (bias ? bias[c] : 0.f);
        out[(size_t)(m0 + r)*ldo + c] = v;
    }
}

// ---------------- generic MHA: 32-query tile per block
__global__ __launch_bounds__(256)
void k_attn(const float* __restrict__ qp, const short* __restrict__ qb16, int ldq,
            const float* __restrict__ kp, const float* __restrict__ vp, int ldkv,
            float* __restrict__ op, int ldo,
            const float* __restrict__ addp,
            int Nq, int Nk, int qtiles)
{
    int bx = blockIdx.x;
    int qt = bx % qtiles;
    int h  = (bx / qtiles) % HEADS;
    int b  = bx / (qtiles * HEADS);
    int q0 = qt * 32;
    const float* kb = kp + (size_t)b*Nk*ldkv + h*HD;
    const float* vb = vp + (size_t)b*Nk*ldkv + h*HD;
    int tid = threadIdx.x;
    __shared__ float Q[32*HD];
    __shared__ float S[32*196];
    for (int e = tid; e < 32*HD; e += 256){
        int r = e >> 6, d = e & 63;
        float qv = 0.f;
        if (q0 + r < Nq){
            size_t qi = (size_t)(b*Nq + q0 + r)*ldq + h*HD + d;
            qv = (qb16 ? b2f(qb16[qi]) : qp[qi]) * SCL;
        }
        Q[e] = qv;
    }
    __syncthreads();
    for (int s = tid; s < 32*Nk; s += 256){
        int qi = s / Nk, ki = s - qi*Nk;
        if (q0 + qi < Nq){
            const float* kr = &kb[(size_t)ki*ldkv];
            float dot = 0.f;
            #pragma unroll 16
            for (int d = 0; d < HD; ++d) dot += Q[qi*HD + d] * kr[d];
            S[qi*196 + ki] = dot;
        }
    }
    __syncthreads();
    {   // softmax: 8 threads per row
        int r = tid >> 3, sub = tid & 7;
        if (q0 + r < Nq){
            float m = -1e30f;
            for (int k = sub; k < Nk; k += 8) m = fmaxf(m, S[r*196 + k]);
            #pragma unroll
            for (int off = 4; off; off >>= 1) m = fmaxf(m, __shfl_xor(m, off, 8));
            float sum = 0.f;
            for (int k = sub; k < Nk; k += 8){
                float e = __expf(S[r*196 + k] - m);
                S[r*196 + k] = e;
                sum += e;
            }
            #pragma unroll
            for (int off = 4; off; off >>= 1) sum += __shfl_xor(sum, off, 8);
            float inv = 1.f / sum;
            for (int k = sub; k < Nk; k += 8) S[r*196 + k] *= inv;
        }
    }
    __syncthreads();
    {   // PV
        int qi = tid >> 3, d0 = (tid & 7) * 8;
        if (q0 + qi < Nq){
            float o[8] = {0,0,0,0,0,0,0,0};
            for (int k = 0; k < Nk; ++k){
                float p = S[qi*196 + k];
                const float* vr = &vb[(size_t)k*ldkv + d0];
                #pragma unroll
                for (int j = 0; j < 8; ++j) o[j] += p * vr[j];
            }
            size_t ob = (size_t)(b*Nq + q0 + qi)*ldo + h*HD + d0;
            #pragma unroll
            for (int j = 0; j < 8; ++j){
                float v = o[j];
                if (addp) v += addp[ob + j];
                op[ob + j] = v;
            }
        }
    }
}

extern "C" void kernel_launch(void* const* d_in, const int* in_sizes, int n_in,
                              void* d_out, int out_size, void* d_ws, size_t ws_size,
                              hipStream_t stream)
{
    const float* x    = (const float*)d_in[0];
    const float* gtok = (const float*)d_in[1];
    const float* dww  = (const float*)d_in[2];
    const float* dwb  = (const float*)d_in[3];
    const float* lng  = (const float*)d_in[4];
    const float* lnb  = (const float*)d_in[5];
    const float* w1   = (const float*)d_in[6];
    const float* b1   = (const float*)d_in[7];
    const float* w2   = (const float*)d_in[8];
    const float* b2   = (const float*)d_in[9];
    const float* gma  = (const float*)d_in[10];
    const float* cbw  = (const float*)d_in[11];
    const float* cbg  = (const float*)d_in[12];
    const float* cbb  = (const float*)d_in[13];
    const float* qkvw = (const float*)d_in[14];
    const float* ugkv = (const float*)d_in[15];
    const float* ugq  = (const float*)d_in[16];
    const float* gbkv = (const float*)d_in[17];
    const float* gbq  = (const float*)d_in[18];
    const float* pw   = (const float*)d_in[19];
    const float* pb   = (const float*)d_in[20];

    float* ws    = (float*)d_ws;
    float* xloc  = ws;                              // [B*N1, 384] f32
    float* pool1 = xloc  + (size_t)NB*N1*DIM;       // [B*N2, 384]
    float* cbout = pool1 + (size_t)NB*N2*DIM;
    float* xd    = cbout + (size_t)NB*N2*DIM;       // [B*N3, 384]
    float* qkv   = xd    + (size_t)NB*N3*DIM;       // [B*N3, 1152]
    float* xds   = qkv   + (size_t)NB*N3*3*DIM;     // [B*N3, 384]
    float* k2v2  = xds   + (size_t)NB*N3*DIM;       // [B*N3, 768]
    float* gq    = k2v2  + (size_t)NB*N3*2*DIM;     // [B*NT, 384]
    float* k3v3  = gq    + (size_t)NB*NT*DIM;       // [B*NT, 768]
    float* wt    = k3v3  + (size_t)NB*NT*2*DIM;     // [9*384*384] f32
    short* xb    = (short*)(wt + (size_t)9*DIM*DIM); // [B*N1,384] bf16 (also reused as q3b)
    short* w1t   = xb    + (size_t)NB*N1*DIM;       // [1536][384] bf16
    short* w2t   = w1t   + (size_t)HIDN*DIM;        // [384][1536] bf16
    short* gbqT  = w2t   + (size_t)DIM*HIDN;        // [384][384]  bf16
    short* pwT   = gbqT  + (size_t)DIM*DIM;         // [384][384]  bf16
    short* q3b   = xb;   // overlay: xb dead after k_mlp_mfma

    float* xout = (float*)d_out;
    float* gt   = xout + (size_t)NB*N1*DIM;

    // weight prep
    k_wt  <<<(DIM*DIM*9 + 255)/256, 256, 0, stream>>>(cbw, wt, DIM*DIM*9);
    k_tcvt<<<(DIM/32)*(HIDN/32), 256, 0, stream>>>(w1, w1t, DIM, HIDN, DIM/32);
    k_tcvt<<<(HIDN/32)*(DIM/32), 256, 0, stream>>>(w2, w2t, HIDN, DIM, HIDN/32);
    k_tcvt<<<(DIM/32)*(DIM/32), 256, 0, stream>>>(gbq, gbqT, DIM, DIM, DIM/32);
    k_tcvt<<<(DIM/32)*(DIM/32), 256, 0, stream>>>(pw, pwT, DIM, DIM, DIM/32);
    // ConvEncoder
    k_dwln<<<NB*N1, 384, 0, stream>>>(x, dww, dwb, lng, lnb, xb);
    k_mlp_mfma<<<NB*N1/64, 256, 0, stream>>>(xb, x, w1t, b1, w2t, b2, gma, xloc);
    // down_1 -> ConvBNReLU -> down_2
    k_pool<<<NB*N2, 384, 0, stream>>>(xloc, pool1, HW);
    k_conv<<<NB*H2*4, 384, 0, stream>>>(pool1, wt, cbg, cbb, cbout);
    k_pool<<<NB*N3, 384, 0, stream>>>(cbout, xd, H2);
    // global aggregation (MHSA over 196 tokens)
    k_gemm<<<(NB*N3/16)*(3*DIM/64), 256, 0, stream>>>(xd, DIM, qkvw, nullptr, qkv, 3*DIM, DIM, 3*DIM/64);
    k_attn<<<NB*HEADS*7, 256, 0, stream>>>(qkv, nullptr, 3*DIM, qkv+DIM, qkv+2*DIM, 3*DIM, xds, DIM, nullptr, N3, N3, 7);
    // global token update
    k_gemm<<<(NB*N3/16)*(2*DIM/64), 256, 0, stream>>>(xds, DIM, ugkv, nullptr, k2v2, 2*DIM, DIM, 2*DIM/64);
    k_gemm<<<(NB*NT/16)*(DIM/64), 256, 0, stream>>>(gtok, DIM, ugq, nullptr, gq, DIM, DIM, DIM/64);
    k_attn<<<NB*HEADS*2, 256, 0, stream>>>(gq, nullptr, DIM, k2v2, k2v2+DIM, 2*DIM, gt, DIM, nullptr, NT, N3, 2);
    // global broadcast
    k_gemm<<<(NB*NT/16)*(2*DIM/64), 256, 0, stream>>>(gt, DIM, gbkv, nullptr, k3v3, 2*DIM, DIM, 2*DIM/64);
    k_gemm_mfma<<<NB*N1/64, 256, 0, stream>>>(x, gbqT, nullptr, nullptr, q3b);
    k_attn<<<NB*HEADS*98, 256, 0, stream>>>(nullptr, q3b, DIM, k3v3, k3v3+DIM, 2*DIM, xloc, DIM, xloc, N1, NT, 98);
    // final projection
    k_gemm_mfma<<<NB*N1/64, 256, 0, stream>>>(xloc, pwT, pb, xout, nullptr);
}

// Round 3
// 2221.487 us; speedup vs baseline: 2.5114x; 1.3616x over previous
//
#include <hip/hip_runtime.h>
#include <hip/hip_bf16.h>
#include <math.h>

#define DIM   384
#define HEADS 6
#define HD    64
#define NB    16      // batch
#define HW    56
#define N1    (HW*HW)   // 3136
#define H2    28
#define N2    (H2*H2)   // 784
#define H3    14
#define N3    (H3*H3)   // 196
#define NT    49        // global tokens
#define HIDN  1536
#define SCL   0.125f
#define PH    30        // padded height for conv input
#define PW    36        // padded width (>=34 so M-pad rows stay in-bounds)

typedef short s8v __attribute__((ext_vector_type(8)));   // 8 bf16 (4 VGPRs)
typedef float f4v __attribute__((ext_vector_type(4)));   // MFMA accumulator

__device__ __forceinline__ short f2b(float f){           // f32 -> bf16 RNE
    unsigned u = __builtin_bit_cast(unsigned, f);
    unsigned r = (u + 0x7FFFu + ((u >> 16) & 1u)) >> 16;
    return (short)r;
}
__device__ __forceinline__ float b2f(short s){
    return __builtin_bit_cast(float, ((unsigned)(unsigned short)s) << 16);
}

// ---------------- conv weight [O,I,3,3] -> bf16 [co][tap][ci]
__global__ void k_wconv(const float* __restrict__ w, short* __restrict__ wtb, int total)
{
    int idx = blockIdx.x * 256 + threadIdx.x;
    if (idx >= total) return;
    int ci  = idx % DIM;
    int tap = (idx / DIM) % 9;
    int co  = idx / (9*DIM);
    wtb[idx] = f2b(w[((size_t)co*DIM + ci)*9 + tap]);
}

// ---------------- tiled transpose + cvt: src f32 [R][C] -> dst bf16 [C][R]
__global__ __launch_bounds__(256)
void k_tcvt(const float* __restrict__ src, short* __restrict__ dst, int R, int C, int rt)
{
    int tile = blockIdx.x;
    int tr = tile % rt, tc = tile / rt;
    int r0 = tr*32, c0 = tc*32;
    int tx = threadIdx.x & 31, ty = threadIdx.x >> 5;
    __shared__ float t[32][33];
    #pragma unroll
    for (int j = 0; j < 4; ++j)
        t[ty + j*8][tx] = src[(size_t)(r0 + ty + j*8)*C + c0 + tx];
    __syncthreads();
    #pragma unroll
    for (int j = 0; j < 4; ++j)
        dst[(size_t)(c0 + ty + j*8)*R + r0 + tx] = f2b(t[tx][ty + j*8]);
}

// ---------------- depthwise 3x3 conv + bias + LayerNorm(1e-6) -> bf16 out
__global__ __launch_bounds__(384)
void k_dwln(const float* __restrict__ x, const float* __restrict__ dww,
            const float* __restrict__ dwb, const float* __restrict__ g,
            const float* __restrict__ bt, short* __restrict__ out)
{
    const int pix = blockIdx.x;           // b*N1 + n
    const int b = pix / N1, n = pix % N1;
    const int h = n / HW, w = n % HW;
    const int c = threadIdx.x;
    float acc = dwb[c];
    #pragma unroll
    for (int kh = 0; kh < 3; ++kh){
        int ih = h + kh - 1; if (ih < 0 || ih >= HW) continue;
        #pragma unroll
        for (int kw = 0; kw < 3; ++kw){
            int iw = w + kw - 1; if (iw < 0 || iw >= HW) continue;
            acc += x[((size_t)(b*N1 + ih*HW + iw))*DIM + c] * dww[c*9 + kh*3 + kw];
        }
    }
    float s = acc, q = acc*acc;
    #pragma unroll
    for (int off = 32; off; off >>= 1){ s += __shfl_down(s, off); q += __shfl_down(q, off); }
    __shared__ float rs[6], rq[6];
    int lane = threadIdx.x & 63, wv = threadIdx.x >> 6;
    if (!lane){ rs[wv] = s; rq[wv] = q; }
    __syncthreads();
    float ts = 0.f, tq = 0.f;
    #pragma unroll
    for (int i = 0; i < 6; ++i){ ts += rs[i]; tq += rq[i]; }
    float mean = ts * (1.f/DIM);
    float var  = tq * (1.f/DIM) - mean*mean;
    float rstd = rsqrtf(var + 1e-6f);
    out[(size_t)pix*DIM + c] = f2b((acc - mean) * rstd * g[c] + bt[c]);
}

// ---------------- fused MFMA MLP: out = x + gamma*( gelu(xb@W1+b1)@W2 + b2 )
#define XS_STR 392
#define HS_STR 72
__global__ __launch_bounds__(256)
void k_mlp_mfma(const short* __restrict__ xb, const float* __restrict__ x,
                const short* __restrict__ w1t, const float* __restrict__ b1,
                const short* __restrict__ w2t, const float* __restrict__ b2,
                const float* __restrict__ gamma, float* __restrict__ out)
{
    __shared__ short Xs[64*XS_STR];
    __shared__ short Hs[64*HS_STR];
    const int t0  = blockIdx.x * 64;
    const int tid = threadIdx.x;
    const int w   = tid >> 6;
    const int l   = tid & 63;
    const int lr  = l & 15;
    const int lg  = l >> 4;

    #pragma unroll
    for (int it = 0; it < 12; ++it){
        int i = tid + it*256;
        int row = i / 48, c8 = (i % 48) * 8;
        *(s8v*)&Xs[row*XS_STR + c8] = *(const s8v*)&xb[(size_t)(t0+row)*DIM + c8];
    }
    __syncthreads();

    f4v a2[4][6];
    #pragma unroll
    for (int m = 0; m < 4; ++m)
        #pragma unroll
        for (int n = 0; n < 6; ++n) a2[m][n] = (f4v){0.f,0.f,0.f,0.f};

    for (int ch = 0; ch < 24; ++ch){
        const int hc0 = ch * 64;
        f4v a1[4];
        #pragma unroll
        for (int m = 0; m < 4; ++m) a1[m] = (f4v){0.f,0.f,0.f,0.f};
        const int col1 = w*16 + lr;
        #pragma unroll 4
        for (int ks = 0; ks < 12; ++ks){
            const int k0 = ks*32 + lg*8;
            s8v bv = *(const s8v*)&w1t[(size_t)(hc0 + col1)*DIM + k0];
            #pragma unroll
            for (int m = 0; m < 4; ++m){
                s8v av = *(const s8v*)&Xs[(m*16 + lr)*XS_STR + k0];
                a1[m] = __builtin_amdgcn_mfma_f32_16x16x32_bf16(av, bv, a1[m], 0, 0, 0);
            }
        }
        float bb1 = b1[hc0 + col1];
        #pragma unroll
        for (int m = 0; m < 4; ++m){
            #pragma unroll
            for (int r = 0; r < 4; ++r){
                float h = a1[m][r] + bb1;
                float gl = h / (1.f + __expf(-1.702f * h));
                Hs[(m*16 + lg*4 + r)*HS_STR + col1] = f2b(gl);
            }
        }
        __syncthreads();
        #pragma unroll
        for (int ks = 0; ks < 2; ++ks){
            const int k0 = ks*32 + lg*8;
            s8v av[4];
            #pragma unroll
            for (int m = 0; m < 4; ++m)
                av[m] = *(const s8v*)&Hs[(m*16 + lr)*HS_STR + k0];
            #pragma unroll
            for (int n = 0; n < 6; ++n){
                s8v bv = *(const s8v*)&w2t[(size_t)(w*96 + n*16 + lr)*HIDN + hc0 + k0];
                #pragma unroll
                for (int m = 0; m < 4; ++m)
                    a2[m][n] = __builtin_amdgcn_mfma_f32_16x16x32_bf16(av[m], bv, a2[m][n], 0, 0, 0);
            }
        }
        __syncthreads();
    }
    #pragma unroll
    for (int n = 0; n < 6; ++n){
        const int col = w*96 + n*16 + lr;
        const float gm = gamma[col], bb2 = b2[col];
        #pragma unroll
        for (int m = 0; m < 4; ++m){
            #pragma unroll
            for (int r = 0; r < 4; ++r){
                size_t idx = (size_t)(t0 + m*16 + lg*4 + r)*DIM + col;
                out[idx] = x[idx] + gm * (a2[m][n][r] + bb2);
            }
        }
    }
}

// ---------------- MFMA GEMM: C[M, colblks*384] = A[M,384] @ WT^T (+bias)
// grid (M/64, colblks); WT is bf16 [N][384] row-major (i.e. W transposed)
__global__ __launch_bounds__(256)
void k_gemm_mfma(const float* __restrict__ A, const short* __restrict__ WT,
                 const float* __restrict__ bias, float* __restrict__ outf,
                 short* __restrict__ outb, int ldo)
{
    __shared__ short As[64*XS_STR];
    const int t0   = blockIdx.x * 64;
    const int col0 = blockIdx.y * 384;
    const int tid = threadIdx.x;
    const int w   = tid >> 6;
    const int l   = tid & 63;
    const int lr  = l & 15;
    const int lg  = l >> 4;

    #pragma unroll
    for (int it = 0; it < 12; ++it){
        int i = tid + it*256;
        int row = i / 48, c8 = (i % 48) * 8;
        const float4* p = (const float4*)&A[(size_t)(t0+row)*DIM + c8];
        float4 u = p[0], v = p[1];
        s8v pk;
        pk[0]=f2b(u.x); pk[1]=f2b(u.y); pk[2]=f2b(u.z); pk[3]=f2b(u.w);
        pk[4]=f2b(v.x); pk[5]=f2b(v.y); pk[6]=f2b(v.z); pk[7]=f2b(v.w);
        *(s8v*)&As[row*XS_STR + c8] = pk;
    }
    __syncthreads();

    f4v a2[4][6];
    #pragma unroll
    for (int m = 0; m < 4; ++m)
        #pragma unroll
        for (int n = 0; n < 6; ++n) a2[m][n] = (f4v){0.f,0.f,0.f,0.f};

    #pragma unroll 4
    for (int ks = 0; ks < 12; ++ks){
        const int k0 = ks*32 + lg*8;
        s8v av[4];
        #pragma unroll
        for (int m = 0; m < 4; ++m)
            av[m] = *(const s8v*)&As[(m*16 + lr)*XS_STR + k0];
        #pragma unroll
        for (int n = 0; n < 6; ++n){
            s8v bv = *(const s8v*)&WT[(size_t)(col0 + w*96 + n*16 + lr)*DIM + k0];
            #pragma unroll
            for (int m = 0; m < 4; ++m)
                a2[m][n] = __builtin_amdgcn_mfma_f32_16x16x32_bf16(av[m], bv, a2[m][n], 0, 0, 0);
        }
    }
    #pragma unroll
    for (int n = 0; n < 6; ++n){
        const int col = col0 + w*96 + n*16 + lr;
        const float bb = bias ? bias[col] : 0.f;
        #pragma unroll
        for (int m = 0; m < 4; ++m){
            #pragma unroll
            for (int r = 0; r < 4; ++r){
                size_t idx = (size_t)(t0 + m*16 + lg*4 + r)*ldo + col;
                float v = a2[m][n][r] + bb;
                if (outb) outb[idx] = f2b(v);
                else      outf[idx] = v;
            }
        }
    }
}

// ---------------- avgpool2 (56->28) + cvt bf16 + write into zero-padded buffer
__global__ __launch_bounds__(384)
void k_poolpad(const float* __restrict__ in, short* __restrict__ pad)
{
    int pix = blockIdx.x;                 // b*N2 + oh*28 + ow
    int b = pix / N2, r = pix % N2;
    int oh = r / H2, ow = r % H2;
    int c = threadIdx.x;
    size_t base = ((size_t)b * HW * HW + (size_t)(2*oh)*HW + 2*ow) * DIM;
    const float* p00 = &in[base];
    const float* p01 = p00 + DIM;
    const float* p10 = p00 + (size_t)HW*DIM;
    const float* p11 = p10 + DIM;
    float v = 0.25f * (p00[c] + p01[c] + p10[c] + p11[c]);
    pad[(((size_t)b*PH + oh + 1)*PW + ow + 1)*DIM + c] = f2b(v);
}

// ---------------- conv 3x3 (384->384, no bias) as implicit MFMA GEMM
// block: 1 output row (28 px, M=32) x 384 co; 4 waves x 96 co; raw f32 out
__global__ __launch_bounds__(256)
void k_conv_mfma(const short* __restrict__ pad, const short* __restrict__ wtb,
                 float* __restrict__ out)
{
    const int bx = blockIdx.x;            // b*28 + oh
    const int oh = bx % H2;
    const int b  = bx / H2;
    const int tid = threadIdx.x;
    const int w   = tid >> 6;
    const int l   = tid & 63;
    const int lr  = l & 15;
    const int lg  = l >> 4;

    f4v acc[2][6];
    #pragma unroll
    for (int m = 0; m < 2; ++m)
        #pragma unroll
        for (int n = 0; n < 6; ++n) acc[m][n] = (f4v){0.f,0.f,0.f,0.f};

    #pragma unroll
    for (int kh = 0; kh < 3; ++kh){
        #pragma unroll
        for (int kw = 0; kw < 3; ++kw){
            const short* Ab = pad + (((size_t)b*PH + oh + kh)*PW + kw)*DIM;
            const short* Bb = wtb + (size_t)(kh*3 + kw)*DIM;
            #pragma unroll 3
            for (int ks = 0; ks < 12; ++ks){
                const int k0 = ks*32 + lg*8;
                s8v a0 = *(const s8v*)&Ab[(size_t)(lr     )*DIM + k0];
                s8v a1 = *(const s8v*)&Ab[(size_t)(lr + 16)*DIM + k0];
                #pragma unroll
                for (int n = 0; n < 6; ++n){
                    s8v bv = *(const s8v*)&Bb[(size_t)(w*96 + n*16 + lr)*(9*DIM) + k0];
                    acc[0][n] = __builtin_amdgcn_mfma_f32_16x16x32_bf16(a0, bv, acc[0][n], 0, 0, 0);
                    acc[1][n] = __builtin_amdgcn_mfma_f32_16x16x32_bf16(a1, bv, acc[1][n], 0, 0, 0);
                }
            }
        }
    }
    #pragma unroll
    for (int n = 0; n < 6; ++n){
        const int col = w*96 + n*16 + lr;
        #pragma unroll
        for (int m = 0; m < 2; ++m){
            #pragma unroll
            for (int r = 0; r < 4; ++r){
                int px = m*16 + lg*4 + r;
                if (px < H2)
                    out[((size_t)(b*N2 + oh*H2 + px))*DIM + col] = acc[m][n][r];
            }
        }
    }
}

// ---------------- LN(1e-5) + ReLU + avgpool2 (28->14): conv raw f32 -> xd f32
__global__ __launch_bounds__(384)
void k_lnpool(const float* __restrict__ conv, const float* __restrict__ g,
              const float* __restrict__ bt, float* __restrict__ out)
{
    int pix = blockIdx.x;                 // b*N3 + oh*14 + ow
    int b = pix / N3, r = pix % N3;
    int oh = r / H3, ow = r % H3;
    int c = threadIdx.x;
    float v[4];
    #pragma unroll
    for (int j = 0; j < 4; ++j){
        int ih = 2*oh + (j >> 1), iw = 2*ow + (j & 1);
        v[j] = conv[((size_t)(b*N2 + ih*H2 + iw))*DIM + c];
    }
    float s[4], q[4];
    #pragma unroll
    for (int j = 0; j < 4; ++j){ s[j] = v[j]; q[j] = v[j]*v[j]; }
    #pragma unroll
    for (int off = 32; off; off >>= 1){
        #pragma unroll
        for (int j = 0; j < 4; ++j){
            s[j] += __shfl_down(s[j], off);
            q[j] += __shfl_down(q[j], off);
        }
    }
    __shared__ float rs[6][4], rq[6][4];
    int lane = threadIdx.x & 63, wv = threadIdx.x >> 6;
    if (!lane){
        #pragma unroll
        for (int j = 0; j < 4; ++j){ rs[wv][j] = s[j]; rq[wv][j] = q[j]; }
    }
    __syncthreads();
    float gc = g[c], bc = bt[c];
    float o = 0.f;
    #pragma unroll
    for (int j = 0; j < 4; ++j){
        float ts = 0.f, tq = 0.f;
        #pragma unroll
        for (int i = 0; i < 6; ++i){ ts += rs[i][j]; tq += rq[i][j]; }
        float mean = ts * (1.f/DIM);
        float var  = tq * (1.f/DIM) - mean*mean;
        float rstd = rsqrtf(var + 1e-5f);
        o += fmaxf((v[j] - mean) * rstd * gc + bc, 0.f);
    }
    out[(size_t)pix*DIM + c] = 0.25f * o;
}

// ---------------- f32 GEMM (small shapes): out[M,N] = A[M,K] @ W[K,N] (+bias)
__global__ __launch_bounds__(256)
void k_gemm(const float* __restrict__ A, int lda,
            const float* __restrict__ W, const float* __restrict__ bias,
            float* __restrict__ out, int ldo, int K, int nb)
{
    int bx = blockIdx.x;
    int m0 = (bx / nb) * 16;
    int cb = (bx % nb) * 64;
    int tid = threadIdx.x;
    int r  = tid >> 4;
    int cg = tid & 15;
    int N  = nb * 64;
    __shared__ float As[16*32];
    __shared__ float Ws[32*64];
    float acc[4] = {0,0,0,0};
    for (int k0 = 0; k0 < K; k0 += 32){
        int e = tid;
        #pragma unroll
        for (int i = 0; i < 2; ++i){
            int rr = e >> 5, kk = e & 31;
            As[rr*32 + kk] = A[(size_t)(m0+rr)*lda + k0 + kk];
            e += 256;
        }
        int f = tid;
        #pragma unroll
        for (int i = 0; i < 8; ++i){
            int kr = f >> 6, cc = f & 63;
            Ws[kr*64 + cc] = W[(size_t)(k0+kr)*N + cb + cc];
            f += 256;
        }
        __syncthreads();
        #pragma unroll 8
        for (int kk = 0; kk < 32; ++kk){
            float a = As[r*32 + kk];
            #pragma unroll
            for (int j = 0; j < 4; ++j)
                acc[j] += a * Ws[kk*64 + cg*4 + j];
        }
        __syncthreads();
    }
    #pragma unroll
    for (int j = 0; j < 4; ++j){
        int c = cb + cg*4 + j;
        float v = acc[j] + (bias ? bias[c] : 0.f);
        out[(size_t)(m0 + r)*ldo + c] = v;
    }
}

// ---------------- generic MHA: 32-query tile per block
__global__ __launch_bounds__(256)
void k_attn(const float* __restrict__ qp, const short* __restrict__ qb16, int ldq,
            const float* __restrict__ kp, const float* __restrict__ vp, int ldkv,
            float* __restrict__ op, int ldo,
            const float* __restrict__ addp,
            int Nq, int Nk, int qtiles)
{
    int bx = blockIdx.x;
    int qt = bx % qtiles;
    int h  = (bx / qtiles) % HEADS;
    int b  = bx / (qtiles * HEADS);
    int q0 = qt * 32;
    const float* kb = kp + (size_t)b*Nk*ldkv + h*HD;
    const float* vb = vp + (size_t)b*Nk*ldkv + h*HD;
    int tid = threadIdx.x;
    __shared__ float Q[32*HD];
    __shared__ float S[32*196];
    for (int e = tid; e < 32*HD; e += 256){
        int r = e >> 6, d = e & 63;
        float qv = 0.f;
        if (q0 + r < Nq){
            size_t qi = (size_t)(b*Nq + q0 + r)*ldq + h*HD + d;
            qv = (qb16 ? b2f(qb16[qi]) : qp[qi]) * SCL;
        }
        Q[e] = qv;
    }
    __syncthreads();
    for (int s = tid; s < 32*Nk; s += 256){
        int qi = s / Nk, ki = s - qi*Nk;
        if (q0 + qi < Nq){
            const float* kr = &kb[(size_t)ki*ldkv];
            float dot = 0.f;
            #pragma unroll 16
            for (int d = 0; d < HD; ++d) dot += Q[qi*HD + d] * kr[d];
            S[qi*196 + ki] = dot;
        }
    }
    __syncthreads();
    {
        int r = tid >> 3, sub = tid & 7;
        if (q0 + r < Nq){
            float m = -1e30f;
            for (int k = sub; k < Nk; k += 8) m = fmaxf(m, S[r*196 + k]);
            #pragma unroll
            for (int off = 4; off; off >>= 1) m = fmaxf(m, __shfl_xor(m, off, 8));
            float sum = 0.f;
            for (int k = sub; k < Nk; k += 8){
                float e = __expf(S[r*196 + k] - m);
                S[r*196 + k] = e;
                sum += e;
            }
            #pragma unroll
            for (int off = 4; off; off >>= 1) sum += __shfl_xor(sum, off, 8);
            float inv = 1.f / sum;
            for (int k = sub; k < Nk; k += 8) S[r*196 + k] *= inv;
        }
    }
    __syncthreads();
    {
        int qi = tid >> 3, d0 = (tid & 7) * 8;
        if (q0 + qi < Nq){
            float o[8] = {0,0,0,0,0,0,0,0};
            for (int k = 0; k < Nk; ++k){
                float p = S[qi*196 + k];
                const float* vr = &vb[(size_t)k*ldkv + d0];
                #pragma unroll
                for (int j = 0; j < 8; ++j) o[j] += p * vr[j];
            }
            size_t ob = (size_t)(b*Nq + q0 + qi)*ldo + h*HD + d0;
            #pragma unroll
            for (int j = 0; j < 8; ++j){
                float v = o[j];
                if (addp) v += addp[ob + j];
                op[ob + j] = v;
            }
        }
    }
}

extern "C" void kernel_launch(void* const* d_in, const int* in_sizes, int n_in,
                              void* d_out, int out_size, void* d_ws, size_t ws_size,
                              hipStream_t stream)
{
    const float* x    = (const float*)d_in[0];
    const float* gtok = (const float*)d_in[1];
    const float* dww  = (const float*)d_in[2];
    const float* dwb  = (const float*)d_in[3];
    const float* lng  = (const float*)d_in[4];
    const float* lnb  = (const float*)d_in[5];
    const float* w1   = (const float*)d_in[6];
    const float* b1   = (const float*)d_in[7];
    const float* w2   = (const float*)d_in[8];
    const float* b2   = (const float*)d_in[9];
    const float* gma  = (const float*)d_in[10];
    const float* cbw  = (const float*)d_in[11];
    const float* cbg  = (const float*)d_in[12];
    const float* cbb  = (const float*)d_in[13];
    const float* qkvw = (const float*)d_in[14];
    const float* ugkv = (const float*)d_in[15];
    const float* ugq  = (const float*)d_in[16];
    const float* gbkv = (const float*)d_in[17];
    const float* gbq  = (const float*)d_in[18];
    const float* pw   = (const float*)d_in[19];
    const float* pb   = (const float*)d_in[20];

    float* ws      = (float*)d_ws;
    float* xloc    = ws;                               // [B*N1,384] f32
    float* convout = xloc    + (size_t)NB*N1*DIM;      // [B*N2,384] f32
    float* xd      = convout + (size_t)NB*N2*DIM;      // [B*N3,384]
    float* qkv     = xd      + (size_t)NB*N3*DIM;      // [B*N3,1152]
    float* xds     = qkv     + (size_t)NB*N3*3*DIM;    // [B*N3,384]
    float* k2v2    = xds     + (size_t)NB*N3*DIM;      // [B*N3,768]
    float* gq      = k2v2    + (size_t)NB*N3*2*DIM;    // [B*NT,384]
    float* k3v3    = gq      + (size_t)NB*NT*DIM;      // [B*NT,768]
    short* xb      = (short*)(k3v3 + (size_t)NB*NT*2*DIM); // [B*N1,384] bf16
    short* pad1    = xb    + (size_t)NB*N1*DIM;        // [B,PH,PW,384] bf16
    short* wtb     = pad1  + (size_t)NB*PH*PW*DIM;     // [384][9][384] bf16
    short* w1t     = wtb   + (size_t)DIM*9*DIM;        // [1536][384]
    short* w2t     = w1t   + (size_t)HIDN*DIM;         // [384][1536]
    short* qkvwT   = w2t   + (size_t)DIM*HIDN;         // [1152][384]
    short* ugkvT   = qkvwT + (size_t)3*DIM*DIM;        // [768][384]
    short* gbqT    = ugkvT + (size_t)2*DIM*DIM;        // [384][384]
    short* pwT     = gbqT  + (size_t)DIM*DIM;          // [384][384]
    short* q3b     = xb;   // overlay: xb dead after k_mlp_mfma

    float* xout = (float*)d_out;
    float* gt   = xout + (size_t)NB*N1*DIM;

    // weight prep
    k_wconv<<<(DIM*9*DIM + 255)/256, 256, 0, stream>>>(cbw, wtb, DIM*9*DIM);
    k_tcvt<<<(DIM/32)*(HIDN/32), 256, 0, stream>>>(w1, w1t, DIM, HIDN, DIM/32);
    k_tcvt<<<(HIDN/32)*(DIM/32), 256, 0, stream>>>(w2, w2t, HIDN, DIM, HIDN/32);
    k_tcvt<<<(DIM/32)*(3*DIM/32), 256, 0, stream>>>(qkvw, qkvwT, DIM, 3*DIM, DIM/32);
    k_tcvt<<<(DIM/32)*(2*DIM/32), 256, 0, stream>>>(ugkv, ugkvT, DIM, 2*DIM, DIM/32);
    k_tcvt<<<(DIM/32)*(DIM/32), 256, 0, stream>>>(gbq, gbqT, DIM, DIM, DIM/32);
    k_tcvt<<<(DIM/32)*(DIM/32), 256, 0, stream>>>(pw, pwT, DIM, DIM, DIM/32);
    // ConvEncoder
    k_dwln<<<NB*N1, 384, 0, stream>>>(x, dww, dwb, lng, lnb, xb);
    k_mlp_mfma<<<NB*N1/64, 256, 0, stream>>>(xb, x, w1t, b1, w2t, b2, gma, xloc);
    // down_1 (pool fused with pad+cvt) -> conv(MFMA) -> LN+ReLU+down_2
    hipMemsetAsync(pad1, 0, (size_t)NB*PH*PW*DIM*sizeof(short), stream);
    k_poolpad<<<NB*N2, 384, 0, stream>>>(xloc, pad1);
    k_conv_mfma<<<NB*H2, 256, 0, stream>>>(pad1, wtb, convout);
    k_lnpool<<<NB*N3, 384, 0, stream>>>(convout, cbg, cbb, xd);
    // global aggregation (MHSA over 196 tokens)
    k_gemm_mfma<<<dim3(NB*N3/64, 3), 256, 0, stream>>>(xd, qkvwT, nullptr, qkv, nullptr, 3*DIM);
    k_attn<<<NB*HEADS*7, 256, 0, stream>>>(qkv, nullptr, 3*DIM, qkv+DIM, qkv+2*DIM, 3*DIM, xds, DIM, nullptr, N3, N3, 7);
    // global token update
    k_gemm_mfma<<<dim3(NB*N3/64, 2), 256, 0, stream>>>(xds, ugkvT, nullptr, k2v2, nullptr, 2*DIM);
    k_gemm<<<(NB*NT/16)*(DIM/64), 256, 0, stream>>>(gtok, DIM, ugq, nullptr, gq, DIM, DIM, DIM/64);
    k_attn<<<NB*HEADS*2, 256, 0, stream>>>(gq, nullptr, DIM, k2v2, k2v2+DIM, 2*DIM, gt, DIM, nullptr, NT, N3, 2);
    // global broadcast
    k_gemm<<<(NB*NT/16)*(2*DIM/64), 256, 0, stream>>>(gt, DIM, gbkv, nullptr, k3v3, 2*DIM, DIM, 2*DIM/64);
    k_gemm_mfma<<<dim3(NB*N1/64, 1), 256, 0, stream>>>(x, gbqT, nullptr, nullptr, q3b, DIM);
    k_attn<<<NB*HEADS*98, 256, 0, stream>>>(nullptr, q3b, DIM, k3v3, k3v3+DIM, 2*DIM, xloc, DIM, xloc, N1, NT, 98);
    // final projection
    k_gemm_mfma<<<dim3(NB*N1/64, 1), 256, 0, stream>>>(xloc, pwT, pb, xout, nullptr, DIM);
}